// Round 6
// baseline (62.633 us; speedup 1.0000x reference)
//
#include <hip/hip_runtime.h>
#include <hip/hip_cooperative_groups.h>
#include <math.h>

namespace cg = cooperative_groups;

#define N_G    512
#define IMG_H  256
#define IMG_W  256

// Single cooperative kernel, 512 blocks x 128 threads (2 blocks/CU).
// Phase 1: global threads 0..511 preprocess one gaussian each -> SoA planes in ws
//   g0[g] = {px, py, cull_rad, tz}   (cull_rad = -1 -> never renders)
//   g1[g] = {conA, conB, conC, op}
//   g2[g] = {col_r, col_g, col_b, 0}
// grid.sync()
// Phase 2: per 16x8 tile: scan -> LDS append -> local stable rank by (tz,idx)
//   (== global stable argsort restricted to covering subset) -> blend.
__global__ __launch_bounds__(128) void gs_fused(
    const float* __restrict__ means3D,
    const float* __restrict__ opacities,
    const float* __restrict__ colors,
    const float* __restrict__ scales,
    const float* __restrict__ rotations,
    const float* __restrict__ viewmatrix,
    const float* __restrict__ projmatrix,
    const float* __restrict__ bg,
    float4* __restrict__ g0,
    float4* __restrict__ g1,
    float4* __restrict__ g2,
    float* __restrict__ img,
    float* __restrict__ radii_out)
{
    const int tid = threadIdx.x;
    const int gthread = blockIdx.x * 128 + tid;

    // ---- Phase 1: preprocess (first 4 blocks do the work)
    if (gthread < N_G) {
        const int g = gthread;
        float VM[16], PM[16];
        #pragma unroll
        for (int i = 0; i < 16; ++i) { VM[i] = viewmatrix[i]; PM[i] = projmatrix[i]; }

        const float mx = means3D[g*3+0], my = means3D[g*3+1], mz = means3D[g*3+2];
        float rq = rotations[g*4+0], xq = rotations[g*4+1], yq = rotations[g*4+2], zq = rotations[g*4+3];
        const float qn = sqrtf(rq*rq + xq*xq + yq*yq + zq*zq);
        rq /= qn; xq /= qn; yq /= qn; zq /= qn;
        const float R00 = 1.f - 2.f*(yq*yq + zq*zq);
        const float R01 = 2.f*(xq*yq - rq*zq);
        const float R02 = 2.f*(xq*zq + rq*yq);
        const float R10 = 2.f*(xq*yq + rq*zq);
        const float R11 = 1.f - 2.f*(xq*xq + zq*zq);
        const float R12 = 2.f*(yq*zq - rq*xq);
        const float R20 = 2.f*(xq*zq - rq*yq);
        const float R21 = 2.f*(yq*zq + rq*xq);
        const float R22 = 1.f - 2.f*(xq*xq + yq*yq);
        float s0 = scales[g*3+0], s1 = scales[g*3+1], s2 = scales[g*3+2];
        s0 *= s0; s1 *= s1; s2 *= s2;
        const float S00 = R00*R00*s0 + R01*R01*s1 + R02*R02*s2;
        const float S01 = R00*R10*s0 + R01*R11*s1 + R02*R12*s2;
        const float S02 = R00*R20*s0 + R01*R21*s1 + R02*R22*s2;
        const float S11 = R10*R10*s0 + R11*R11*s1 + R12*R12*s2;
        const float S12 = R10*R20*s0 + R11*R21*s1 + R12*R22*s2;
        const float S22 = R20*R20*s0 + R21*R21*s1 + R22*R22*s2;

        const float pv0 = VM[0]*mx + VM[1]*my + VM[2]*mz  + VM[3];
        const float pv1 = VM[4]*mx + VM[5]*my + VM[6]*mz  + VM[7];
        const float tz  = VM[8]*mx + VM[9]*my + VM[10]*mz + VM[11];
        const float FX = 256.f, FY = 256.f, limx = 0.65f, limy = 0.65f;
        const float tx = fminf(fmaxf(pv0/tz, -limx), limx) * tz;
        const float ty = fminf(fmaxf(pv1/tz, -limy), limy) * tz;
        const float itz = 1.f / tz, itz2 = itz*itz;
        const float J00 = FX*itz, J02 = -FX*tx*itz2;
        const float J11 = FY*itz, J12 = -FY*ty*itz2;
        const float T00 = J00*VM[0] + J02*VM[8];
        const float T01 = J00*VM[1] + J02*VM[9];
        const float T02 = J00*VM[2] + J02*VM[10];
        const float T10 = J11*VM[4] + J12*VM[8];
        const float T11 = J11*VM[5] + J12*VM[9];
        const float T12 = J11*VM[6] + J12*VM[10];
        const float u0 = T00*S00 + T01*S01 + T02*S02;
        const float u1 = T00*S01 + T01*S11 + T02*S12;
        const float u2 = T00*S02 + T01*S12 + T02*S22;
        const float v0 = T10*S00 + T11*S01 + T12*S02;
        const float v1 = T10*S01 + T11*S11 + T12*S12;
        const float v2 = T10*S02 + T11*S12 + T12*S22;
        const float c00 = u0*T00 + u1*T01 + u2*T02;
        const float c01 = u0*T10 + u1*T11 + u2*T12;
        const float c11 = v0*T10 + v1*T11 + v2*T12;
        const float a = c00 + 0.3f, b = c01, c = c11 + 0.3f;
        const float det = a*c - b*b;
        const float inv_det = 1.f/det;
        float conA = c*inv_det, conB = -b*inv_det, conC = a*inv_det;
        const float ph0 = PM[0]*mx  + PM[1]*my  + PM[2]*mz  + PM[3];
        const float ph1 = PM[4]*mx  + PM[5]*my  + PM[6]*mz  + PM[7];
        const float ph3 = PM[12]*mx + PM[13]*my + PM[14]*mz + PM[15];
        const float pw = 1.f/(ph3 + 1e-7f);
        const float pix_x = ((ph0*pw + 1.f)*(float)IMG_W - 1.f)*0.5f;
        const float pix_y = ((ph1*pw + 1.f)*(float)IMG_H - 1.f)*0.5f;
        const float mid = 0.5f*(a + c);
        const float lam = mid + sqrtf(fmaxf(0.1f, mid*mid - det));
        const bool valid = (tz > 0.2f) && (det > 0.f);
        float op = opacities[g];
        if (!valid) { conA = conB = conC = 0.f; op = 0.f; }

        radii_out[g] = valid ? ceilf(3.f*sqrtf(lam)) : 0.f;

        // Conservative cull radius: al >= 1/255 needs |d|^2 <= 2*lam*ln(255*op)
        // (lam >= lambda_max of regularized cov2d: sqrt arg clamped upward).
        float rad = -1.f;
        if (valid && op * 255.f > 1.f) {
            const float r = sqrtf(2.f * lam * logf(255.f * op)) + 0.01f;
            if (pix_x + r >= 0.f && pix_x - r <= (float)(IMG_W-1) &&
                pix_y + r >= 0.f && pix_y - r <= (float)(IMG_H-1))
                rad = r;
        }

        g0[g] = make_float4(pix_x, pix_y, rad, tz);
        g1[g] = make_float4(conA, conB, conC, op);
        g2[g] = make_float4(colors[g*3+0], colors[g*3+1], colors[g*3+2], 0.f);
    }

    cg::this_grid().sync();

    // ---- Phase 2: rasterize one 16x8 tile per block
    __shared__ int   s_n;
    __shared__ float s_tz[N_G];
    __shared__ int   s_id[N_G];
    __shared__ float4 c0[N_G];          // {px,py,A,B}  depth-ordered
    __shared__ float4 c1[N_G];          // {C,op,cr,cg}
    __shared__ float  c2[N_G];          // {cb}

    if (tid == 0) s_n = 0;
    __syncthreads();

    const int bx = blockIdx.x & 15, by = blockIdx.x >> 4;   // 16 x 32 tiles of 16x8
    const float x0 = (float)(bx * 16), x1 = x0 + 15.f;
    const float y0 = (float)(by * 8),  y1 = y0 + 7.f;

    #pragma unroll
    for (int gi = 0; gi < 4; ++gi) {
        const int g = tid + gi * 128;
        const float4 w = g0[g];
        if (w.z > 0.f &&
            w.x + w.z >= x0 && w.x - w.z <= x1 &&
            w.y + w.z >= y0 && w.y - w.z <= y1) {
            const int p = atomicAdd(&s_n, 1);
            s_tz[p] = w.w;
            s_id[p] = g;
        }
    }
    __syncthreads();

    const int nc  = s_n;
    const int ncp = (nc + 7) & ~7;

    for (int i = tid; i < nc; i += 128) {
        const float tz = s_tz[i];
        const int   id = s_id[i];
        int r = 0;
        #pragma unroll 8
        for (int j = 0; j < nc; ++j) {
            const float tj = s_tz[j];
            r += (tj < tz) || (tj == tz && s_id[j] < id);
        }
        const float4 a0 = g0[id];   // L2-warm scattered reads
        const float4 a1 = g1[id];
        const float4 a2 = g2[id];
        c0[r] = make_float4(a0.x, a0.y, a1.x, a1.y);
        c1[r] = make_float4(a1.z, a1.w, a2.x, a2.y);
        c2[r] = a2.z;
    }
    for (int i = nc + tid; i < ncp; i += 128) {  // zero pad: al=0 -> skipped, no NaN
        c0[i] = make_float4(0.f, 0.f, 0.f, 0.f);
        c1[i] = make_float4(0.f, 0.f, 0.f, 0.f);
        c2[i] = 0.f;
    }
    __syncthreads();

    const int lx = tid & 15, ly = tid >> 4;
    const int px = bx * 16 + lx, py = by * 8 + ly;
    const float fx = (float)px, fy = (float)py;

    float T = 1.f, cr = 0.f, cg = 0.f, cb = 0.f;
    bool done = false;
    for (int base = 0; base < ncp; base += 8) {
        #pragma unroll
        for (int u = 0; u < 8; ++u) {
            const int i = base + u;
            const float4 p0 = c0[i];
            const float4 p1 = c1[i];
            const float  pb = c2[i];
            const float dx = p0.x - fx;
            const float dy = p0.y - fy;
            const float power = -0.5f*(p0.z*dx*dx + p1.x*dy*dy) - p0.w*dx*dy;
            const float al = fminf(0.99f, p1.y*__expf(power));
            if (!done && !(power > 0.f || al < (1.0f/255.0f))) {
                const float Tnew = T * (1.f - al);
                if (Tnew < 1e-4f) { T = Tnew; done = true; }
                else {
                    const float wgt = al * T;
                    cr += wgt * p1.z;
                    cg += wgt * p1.w;
                    cb += wgt * pb;
                    T = Tnew;
                }
            }
        }
        if (__all(done)) break;
    }
    const int pix = py * IMG_W + px;
    img[pix]                   = cr + T * bg[0];
    img[IMG_H*IMG_W   + pix]   = cg + T * bg[1];
    img[2*IMG_H*IMG_W + pix]   = cb + T * bg[2];
}

extern "C" void kernel_launch(void* const* d_in, const int* in_sizes, int n_in,
                              void* d_out, int out_size, void* d_ws, size_t ws_size,
                              hipStream_t stream) {
    const float* means3D    = (const float*)d_in[0];
    // d_in[1] = means2D (unused by reference math)
    const float* opacities  = (const float*)d_in[2];
    const float* colors     = (const float*)d_in[3];
    const float* scales     = (const float*)d_in[4];
    const float* rotations  = (const float*)d_in[5];
    const float* viewmatrix = (const float*)d_in[6];
    const float* projmatrix = (const float*)d_in[7];
    const float* bg         = (const float*)d_in[8];

    float* img   = (float*)d_out;                   // 3*256*256
    float* radii = (float*)d_out + 3*IMG_H*IMG_W;   // 512 (as float values)
    float4* g0   = (float4*)d_ws;                   // 512 float4
    float4* g1   = g0 + N_G;
    float4* g2   = g1 + N_G;

    void* args[] = {
        (void*)&means3D, (void*)&opacities, (void*)&colors, (void*)&scales,
        (void*)&rotations, (void*)&viewmatrix, (void*)&projmatrix, (void*)&bg,
        (void*)&g0, (void*)&g1, (void*)&g2, (void*)&img, (void*)&radii
    };
    hipLaunchCooperativeKernel((void*)gs_fused,
                               dim3((IMG_W/16)*(IMG_H/8)), dim3(128),
                               args, 0, stream);
}

// Round 7
// 31.514 us; speedup vs baseline: 1.9875x; 1.9875x over previous
//
#include <hip/hip_runtime.h>
#include <hip/hip_fp16.h>
#include <math.h>

#define N_G    512
#define IMG_H  256
#define IMG_W  256

// Kernel A: 1 block x 512 threads. Full per-gaussian preprocess in registers,
// stable counting-rank by depth tz (== jnp.argsort stable ascending), scatter
// DEPTH-SORTED packed planes into ws:
//   Gs[r] = {px, py, cull_rad, 0}                  (scan plane; rad<0 = culled)
//   Ga[r] = {px, py, -0.5*conA, -conB}             (blend plane A)
//   Gb[r] = {-0.5*conC, ln(op), half2(cr,cg), cb}  (blend plane B)
__global__ __launch_bounds__(512) void gs_prep(
    const float* __restrict__ means3D,
    const float* __restrict__ opacities,
    const float* __restrict__ colors,
    const float* __restrict__ scales,
    const float* __restrict__ rotations,
    const float* __restrict__ viewmatrix,
    const float* __restrict__ projmatrix,
    float4* __restrict__ Gs,
    float4* __restrict__ Ga,
    float4* __restrict__ Gb,
    float* __restrict__ radii_out)
{
    __shared__ float skey[N_G];
    const int g = threadIdx.x;

    float VM[16], PM[16];
    #pragma unroll
    for (int i = 0; i < 16; ++i) { VM[i] = viewmatrix[i]; PM[i] = projmatrix[i]; }

    const float mx = means3D[g*3+0], my = means3D[g*3+1], mz = means3D[g*3+2];
    float rq = rotations[g*4+0], xq = rotations[g*4+1], yq = rotations[g*4+2], zq = rotations[g*4+3];
    const float qn = sqrtf(rq*rq + xq*xq + yq*yq + zq*zq);
    rq /= qn; xq /= qn; yq /= qn; zq /= qn;
    const float R00 = 1.f - 2.f*(yq*yq + zq*zq);
    const float R01 = 2.f*(xq*yq - rq*zq);
    const float R02 = 2.f*(xq*zq + rq*yq);
    const float R10 = 2.f*(xq*yq + rq*zq);
    const float R11 = 1.f - 2.f*(xq*xq + zq*zq);
    const float R12 = 2.f*(yq*zq - rq*xq);
    const float R20 = 2.f*(xq*zq - rq*yq);
    const float R21 = 2.f*(yq*zq + rq*xq);
    const float R22 = 1.f - 2.f*(xq*xq + yq*yq);
    float s0 = scales[g*3+0], s1 = scales[g*3+1], s2 = scales[g*3+2];
    s0 *= s0; s1 *= s1; s2 *= s2;
    const float S00 = R00*R00*s0 + R01*R01*s1 + R02*R02*s2;
    const float S01 = R00*R10*s0 + R01*R11*s1 + R02*R12*s2;
    const float S02 = R00*R20*s0 + R01*R21*s1 + R02*R22*s2;
    const float S11 = R10*R10*s0 + R11*R11*s1 + R12*R12*s2;
    const float S12 = R10*R20*s0 + R11*R21*s1 + R12*R22*s2;
    const float S22 = R20*R20*s0 + R21*R21*s1 + R22*R22*s2;

    const float pv0 = VM[0]*mx + VM[1]*my + VM[2]*mz  + VM[3];
    const float pv1 = VM[4]*mx + VM[5]*my + VM[6]*mz  + VM[7];
    const float tz  = VM[8]*mx + VM[9]*my + VM[10]*mz + VM[11];
    const float FX = 256.f, FY = 256.f, limx = 0.65f, limy = 0.65f;
    const float tx = fminf(fmaxf(pv0/tz, -limx), limx) * tz;
    const float ty = fminf(fmaxf(pv1/tz, -limy), limy) * tz;
    const float itz = 1.f / tz, itz2 = itz*itz;
    const float J00 = FX*itz, J02 = -FX*tx*itz2;
    const float J11 = FY*itz, J12 = -FY*ty*itz2;
    const float T00 = J00*VM[0] + J02*VM[8];
    const float T01 = J00*VM[1] + J02*VM[9];
    const float T02 = J00*VM[2] + J02*VM[10];
    const float T10 = J11*VM[4] + J12*VM[8];
    const float T11 = J11*VM[5] + J12*VM[9];
    const float T12 = J11*VM[6] + J12*VM[10];
    const float u0 = T00*S00 + T01*S01 + T02*S02;
    const float u1 = T00*S01 + T01*S11 + T02*S12;
    const float u2 = T00*S02 + T01*S12 + T02*S22;
    const float v0 = T10*S00 + T11*S01 + T12*S02;
    const float v1 = T10*S01 + T11*S11 + T12*S12;
    const float v2 = T10*S02 + T11*S12 + T12*S22;
    const float c00 = u0*T00 + u1*T01 + u2*T02;
    const float c01 = u0*T10 + u1*T11 + u2*T12;
    const float c11 = v0*T10 + v1*T11 + v2*T12;
    const float a = c00 + 0.3f, b = c01, c = c11 + 0.3f;
    const float det = a*c - b*b;
    const float inv_det = 1.f/det;
    float conA = c*inv_det, conB = -b*inv_det, conC = a*inv_det;
    const float ph0 = PM[0]*mx  + PM[1]*my  + PM[2]*mz  + PM[3];
    const float ph1 = PM[4]*mx  + PM[5]*my  + PM[6]*mz  + PM[7];
    const float ph3 = PM[12]*mx + PM[13]*my + PM[14]*mz + PM[15];
    const float pw = 1.f/(ph3 + 1e-7f);
    const float pix_x = ((ph0*pw + 1.f)*(float)IMG_W - 1.f)*0.5f;
    const float pix_y = ((ph1*pw + 1.f)*(float)IMG_H - 1.f)*0.5f;
    const float mid = 0.5f*(a + c);
    const float lam = mid + sqrtf(fmaxf(0.1f, mid*mid - det));
    const bool valid = (tz > 0.2f) && (det > 0.f);
    float op = opacities[g];
    if (!valid) { conA = conB = conC = 0.f; op = 0.f; }

    radii_out[g] = valid ? ceilf(3.f*sqrtf(lam)) : 0.f;

    // Conservative cull radius: al >= 1/255 needs |d|^2 <= 2*lam*ln(255*op)
    // (lam >= lambda_max of regularized cov2d: sqrt arg is clamped upward).
    float rad = -1.f;
    if (valid && op * 255.f > 1.f) {
        const float r = sqrtf(2.f * lam * logf(255.f * op)) + 0.01f;
        if (pix_x + r >= 0.f && pix_x - r <= (float)(IMG_W-1) &&
            pix_y + r >= 0.f && pix_y - r <= (float)(IMG_H-1))
            rad = r;
    }

    skey[g] = tz;
    __syncthreads();

    // stable counting-rank on (tz, idx)
    int rk = 0;
    #pragma unroll 16
    for (int j = 0; j < N_G; ++j) {
        const float kj = skey[j];
        rk += (kj < tz) || (kj == tz && j < g);
    }

    const float lnop = logf(op);   // op==0 -> -inf -> alpha 0 (and rad<0 anyway)
    const float rg = __builtin_bit_cast(float, __floats2half2_rn(colors[g*3+0], colors[g*3+1]));
    Gs[rk] = make_float4(pix_x, pix_y, rad, 0.f);
    Ga[rk] = make_float4(pix_x, pix_y, -0.5f*conA, -conB);
    Gb[rk] = make_float4(-0.5f*conC, lnop, rg, colors[g*3+2]);
}

// Kernel B: 1024 blocks x 64 threads (one wave), one 8x8 tile per block.
// Scan the depth-sorted list; ballot + mbcnt in-order compaction into LDS
// (order preserved == depth order, so no per-tile sort needed); blend.
__global__ __launch_bounds__(64) void gs_raster(
    const float4* __restrict__ Gs,
    const float4* __restrict__ Ga,
    const float4* __restrict__ Gb,
    const float* __restrict__ bg,
    float* __restrict__ img)
{
    __shared__ float4 cA[N_G];   // {px,py,-0.5A,-B}   depth-ordered compact
    __shared__ float4 cB[N_G];   // {-0.5C,lnop,rg_h2,cb}

    const int lane = threadIdx.x;
    const int bx = blockIdx.x & 31, by = blockIdx.x >> 5;   // 32x32 tiles of 8x8
    const float x0 = (float)(bx * 8), x1 = x0 + 7.f;
    const float y0 = (float)(by * 8), y1 = y0 + 7.f;

    // scan 8 chunks of 64; in-order (= depth-order) append via ballot prefix
    int n = 0;
    #pragma unroll
    for (int k = 0; k < 8; ++k) {
        const int g = k * 64 + lane;
        const float4 w = Gs[g];
        const bool hit = (w.z > 0.f &&
                          w.x + w.z >= x0 && w.x - w.z <= x1 &&
                          w.y + w.z >= y0 && w.y - w.z <= y1);
        const unsigned long long mask = __ballot(hit);
        if (hit) {
            const int pre = __builtin_amdgcn_mbcnt_hi(
                (unsigned)(mask >> 32),
                __builtin_amdgcn_mbcnt_lo((unsigned)mask, 0));
            const int pos = n + pre;
            cA[pos] = Ga[g];
            cB[pos] = Gb[g];
        }
        n += __popcll(mask);
    }
    const int ncp = (n + 7) & ~7;
    for (int i = n + lane; i < ncp; i += 64) {   // pad: lnop=-1e30 -> al=0 -> skipped
        cA[i] = make_float4(0.f, 0.f, 0.f, 0.f);
        cB[i] = make_float4(0.f, -1e30f, 0.f, 0.f);
    }
    __syncthreads();   // single-wave: cheap; orders LDS writes before reads

    // front-to-back blend, one pixel per lane
    const int px = bx * 8 + (lane & 7), py = by * 8 + (lane >> 3);
    const float fx = (float)px, fy = (float)py;

    float T = 1.f, cr = 0.f, cg = 0.f, cb = 0.f;
    bool done = false;
    for (int base = 0; base < ncp; base += 8) {
        #pragma unroll
        for (int u = 0; u < 8; ++u) {
            const int i = base + u;
            const float4 pA = cA[i];
            const float4 pB = cB[i];
            const float dx = pA.x - fx;
            const float dy = pA.y - fy;
            const float power = pA.z*dx*dx + pA.w*dx*dy + pB.x*dy*dy;
            const float al = fminf(0.99f, __expf(power + pB.y));
            if (!done && !(power > 0.f || al < (1.0f/255.0f))) {
                const float Tnew = T * (1.f - al);
                if (Tnew < 1e-4f) { T = Tnew; done = true; }
                else {
                    const float wgt = al * T;
                    const float2 rg = __half22float2(__builtin_bit_cast(__half2, pB.z));
                    cr += wgt * rg.x;
                    cg += wgt * rg.y;
                    cb += wgt * pB.w;
                    T = Tnew;
                }
            }
        }
        if (__all(done)) break;
    }
    const int pix = py * IMG_W + px;
    img[pix]                   = cr + T * bg[0];
    img[IMG_H*IMG_W   + pix]   = cg + T * bg[1];
    img[2*IMG_H*IMG_W + pix]   = cb + T * bg[2];
}

extern "C" void kernel_launch(void* const* d_in, const int* in_sizes, int n_in,
                              void* d_out, int out_size, void* d_ws, size_t ws_size,
                              hipStream_t stream) {
    const float* means3D    = (const float*)d_in[0];
    // d_in[1] = means2D (unused by reference math)
    const float* opacities  = (const float*)d_in[2];
    const float* colors     = (const float*)d_in[3];
    const float* scales     = (const float*)d_in[4];
    const float* rotations  = (const float*)d_in[5];
    const float* viewmatrix = (const float*)d_in[6];
    const float* projmatrix = (const float*)d_in[7];
    const float* bg         = (const float*)d_in[8];

    float* img   = (float*)d_out;                   // 3*256*256
    float* radii = (float*)d_out + 3*IMG_H*IMG_W;   // 512 (as float values)
    float4* Gs   = (float4*)d_ws;                   // 512 float4 each
    float4* Ga   = Gs + N_G;
    float4* Gb   = Ga + N_G;

    gs_prep<<<1, N_G, 0, stream>>>(means3D, opacities, colors, scales,
                                   rotations, viewmatrix, projmatrix,
                                   Gs, Ga, Gb, radii);
    gs_raster<<<(IMG_W/8)*(IMG_H/8), 64, 0, stream>>>(Gs, Ga, Gb, bg, img);
}

// Round 8
// 30.783 us; speedup vs baseline: 2.0347x; 1.0237x over previous
//
#include <hip/hip_runtime.h>
#include <hip/hip_fp16.h>
#include <math.h>

#define N_G    512
#define IMG_H  256
#define IMG_W  256

// Kernel A: 1 block x 512 threads. Per-gaussian preprocess in registers,
// stable counting-rank by depth tz (== stable jnp.argsort), scatter
// DEPTH-SORTED packed planes into ws:
//   Gs[r] = {px, py, cull_rad, 0}            (scan plane; rad<0 = culled)
//   Ga[r] = {-0.5A, -B, -0.5C, ln(op)}       (blend quadratic plane)
//   Gb[r] = {half2(col_r,col_g), col_b}      (color plane, float2)
__global__ __launch_bounds__(512) void gs_prep(
    const float* __restrict__ means3D,
    const float* __restrict__ opacities,
    const float* __restrict__ colors,
    const float* __restrict__ scales,
    const float* __restrict__ rotations,
    const float* __restrict__ viewmatrix,
    const float* __restrict__ projmatrix,
    float4* __restrict__ Gs,
    float4* __restrict__ Ga,
    float2* __restrict__ Gb,
    float* __restrict__ radii_out)
{
    __shared__ float skey[N_G];
    const int g = threadIdx.x;

    float VM[16], PM[16];
    #pragma unroll
    for (int i = 0; i < 16; ++i) { VM[i] = viewmatrix[i]; PM[i] = projmatrix[i]; }

    const float mx = means3D[g*3+0], my = means3D[g*3+1], mz = means3D[g*3+2];
    float rq = rotations[g*4+0], xq = rotations[g*4+1], yq = rotations[g*4+2], zq = rotations[g*4+3];
    const float qn = sqrtf(rq*rq + xq*xq + yq*yq + zq*zq);
    rq /= qn; xq /= qn; yq /= qn; zq /= qn;
    const float R00 = 1.f - 2.f*(yq*yq + zq*zq);
    const float R01 = 2.f*(xq*yq - rq*zq);
    const float R02 = 2.f*(xq*zq + rq*yq);
    const float R10 = 2.f*(xq*yq + rq*zq);
    const float R11 = 1.f - 2.f*(xq*xq + zq*zq);
    const float R12 = 2.f*(yq*zq - rq*xq);
    const float R20 = 2.f*(xq*zq - rq*yq);
    const float R21 = 2.f*(yq*zq + rq*xq);
    const float R22 = 1.f - 2.f*(xq*xq + yq*yq);
    float s0 = scales[g*3+0], s1 = scales[g*3+1], s2 = scales[g*3+2];
    s0 *= s0; s1 *= s1; s2 *= s2;
    const float S00 = R00*R00*s0 + R01*R01*s1 + R02*R02*s2;
    const float S01 = R00*R10*s0 + R01*R11*s1 + R02*R12*s2;
    const float S02 = R00*R20*s0 + R01*R21*s1 + R02*R22*s2;
    const float S11 = R10*R10*s0 + R11*R11*s1 + R12*R12*s2;
    const float S12 = R10*R20*s0 + R11*R21*s1 + R12*R22*s2;
    const float S22 = R20*R20*s0 + R21*R21*s1 + R22*R22*s2;

    const float pv0 = VM[0]*mx + VM[1]*my + VM[2]*mz  + VM[3];
    const float pv1 = VM[4]*mx + VM[5]*my + VM[6]*mz  + VM[7];
    const float tz  = VM[8]*mx + VM[9]*my + VM[10]*mz + VM[11];
    const float FX = 256.f, FY = 256.f, limx = 0.65f, limy = 0.65f;
    const float tx = fminf(fmaxf(pv0/tz, -limx), limx) * tz;
    const float ty = fminf(fmaxf(pv1/tz, -limy), limy) * tz;
    const float itz = 1.f / tz, itz2 = itz*itz;
    const float J00 = FX*itz, J02 = -FX*tx*itz2;
    const float J11 = FY*itz, J12 = -FY*ty*itz2;
    const float T00 = J00*VM[0] + J02*VM[8];
    const float T01 = J00*VM[1] + J02*VM[9];
    const float T02 = J00*VM[2] + J02*VM[10];
    const float T10 = J11*VM[4] + J12*VM[8];
    const float T11 = J11*VM[5] + J12*VM[9];
    const float T12 = J11*VM[6] + J12*VM[10];
    const float u0 = T00*S00 + T01*S01 + T02*S02;
    const float u1 = T00*S01 + T01*S11 + T02*S12;
    const float u2 = T00*S02 + T01*S12 + T02*S22;
    const float v0 = T10*S00 + T11*S01 + T12*S02;
    const float v1 = T10*S01 + T11*S11 + T12*S12;
    const float v2 = T10*S02 + T11*S12 + T12*S22;
    const float c00 = u0*T00 + u1*T01 + u2*T02;
    const float c01 = u0*T10 + u1*T11 + u2*T12;
    const float c11 = v0*T10 + v1*T11 + v2*T12;
    const float a = c00 + 0.3f, b = c01, c = c11 + 0.3f;
    const float det = a*c - b*b;
    const float inv_det = 1.f/det;
    float conA = c*inv_det, conB = -b*inv_det, conC = a*inv_det;
    const float ph0 = PM[0]*mx  + PM[1]*my  + PM[2]*mz  + PM[3];
    const float ph1 = PM[4]*mx  + PM[5]*my  + PM[6]*mz  + PM[7];
    const float ph3 = PM[12]*mx + PM[13]*my + PM[14]*mz + PM[15];
    const float pw = 1.f/(ph3 + 1e-7f);
    const float pix_x = ((ph0*pw + 1.f)*(float)IMG_W - 1.f)*0.5f;
    const float pix_y = ((ph1*pw + 1.f)*(float)IMG_H - 1.f)*0.5f;
    const float mid = 0.5f*(a + c);
    const float lam = mid + sqrtf(fmaxf(0.1f, mid*mid - det));
    const bool valid = (tz > 0.2f) && (det > 0.f);
    float op = opacities[g];
    if (!valid) { conA = conB = conC = 0.f; op = 0.f; }

    radii_out[g] = valid ? ceilf(3.f*sqrtf(lam)) : 0.f;

    // Conservative cull radius: al >= 1/255 needs |d|^2 <= 2*lam*ln(255*op)
    // (lam >= lambda_max of regularized cov2d: sqrt arg is clamped upward).
    float rad = -1.f;
    if (valid && op * 255.f > 1.f) {
        const float r = sqrtf(2.f * lam * logf(255.f * op)) + 0.01f;
        if (pix_x + r >= 0.f && pix_x - r <= (float)(IMG_W-1) &&
            pix_y + r >= 0.f && pix_y - r <= (float)(IMG_H-1))
            rad = r;
    }

    skey[g] = tz;
    __syncthreads();

    // stable counting-rank on (tz, idx)
    int rk = 0;
    #pragma unroll 16
    for (int j = 0; j < N_G; ++j) {
        const float kj = skey[j];
        rk += (kj < tz) || (kj == tz && j < g);
    }

    const float lnop = logf(op);   // op==0 -> -inf -> alpha 0 (and rad<0 anyway)
    const float rg = __builtin_bit_cast(float, __floats2half2_rn(colors[g*3+0], colors[g*3+1]));
    Gs[rk] = make_float4(pix_x, pix_y, rad, 0.f);
    Ga[rk] = make_float4(-0.5f*conA, -conB, -0.5f*conC, lnop);
    Gb[rk] = make_float2(rg, colors[g*3+2]);
}

// Kernel B: 1024 blocks x 64 threads (one wave), one 8x8 tile per block
// (4 blocks/CU). SINGLE memory epoch: unconditionally stage all 8 strided
// gaussians' scan+blend planes into registers (24 independent loads, one
// vmcnt drain), then 8 back-to-back ballots do in-order (= depth-order)
// compaction into LDS, then blend. No rank loop, no second gather epoch.
__global__ __launch_bounds__(64) void gs_raster(
    const float4* __restrict__ Gs,
    const float4* __restrict__ Ga,
    const float2* __restrict__ Gb,
    const float* __restrict__ bg,
    float* __restrict__ img)
{
    __shared__ float2 cP[N_G];   // {px,py}
    __shared__ float4 cA[N_G];   // {-0.5A,-B,-0.5C,lnop}
    __shared__ float2 cC[N_G];   // {rg_half2, cb}

    const int lane = threadIdx.x;
    const int bx = blockIdx.x & 31, by = blockIdx.x >> 5;   // 32x32 grid of 8x8 tiles
    const float x0 = (float)(bx * 8), x1 = x0 + 7.f;
    const float y0 = (float)(by * 8), y1 = y0 + 7.f;

    // stage everything (fully unrolled -> static reg indices, one load burst)
    float4 s[8], a[8];
    float2 c[8];
    #pragma unroll
    for (int k = 0; k < 8; ++k) {
        const int g = k * 64 + lane;
        s[k] = Gs[g];
        a[k] = Ga[g];
        c[k] = Gb[g];
    }

    // in-order ballot compaction (input is depth-sorted, order preserved)
    int total = 0;
    #pragma unroll
    for (int k = 0; k < 8; ++k) {
        const bool hit = (s[k].z > 0.f &&
                          s[k].x + s[k].z >= x0 && s[k].x - s[k].z <= x1 &&
                          s[k].y + s[k].z >= y0 && s[k].y - s[k].z <= y1);
        const unsigned long long mask = __ballot(hit);
        if (hit) {
            const int pos = total + __builtin_amdgcn_mbcnt_hi(
                (unsigned)(mask >> 32),
                __builtin_amdgcn_mbcnt_lo((unsigned)mask, 0));
            cP[pos] = make_float2(s[k].x, s[k].y);
            cA[pos] = a[k];
            cC[pos] = c[k];
        }
        total += __popcll(mask);
    }
    const int ncp = (total + 7) & ~7;
    for (int i = total + lane; i < ncp; i += 64) {  // pad: lnop=-1e30 -> skipped
        cP[i] = make_float2(0.f, 0.f);
        cA[i] = make_float4(0.f, 0.f, 0.f, -1e30f);
        cC[i] = make_float2(0.f, 0.f);
    }
    __syncthreads();

    // front-to-back blend, one pixel per lane
    const int px = bx * 8 + (lane & 7), py = by * 8 + (lane >> 3);
    const float fx = (float)px, fy = (float)py;

    float T = 1.f, cr = 0.f, cg = 0.f, cb = 0.f;
    bool done = false;
    for (int base = 0; base < ncp; base += 8) {
        #pragma unroll
        for (int u = 0; u < 8; ++u) {
            const int i = base + u;
            const float2 pP = cP[i];
            const float4 pA = cA[i];
            const float2 pC = cC[i];
            const float dx = pP.x - fx;
            const float dy = pP.y - fy;
            const float power = pA.x*dx*dx + pA.y*dx*dy + pA.z*dy*dy;
            const float al = fminf(0.99f, __expf(power + pA.w));
            if (!done && !(power > 0.f || al < (1.0f/255.0f))) {
                const float Tnew = T * (1.f - al);
                if (Tnew < 1e-4f) { T = Tnew; done = true; }
                else {
                    const float wgt = al * T;
                    const float2 rg = __half22float2(__builtin_bit_cast(__half2, pC.x));
                    cr += wgt * rg.x;
                    cg += wgt * rg.y;
                    cb += wgt * pC.y;
                    T = Tnew;
                }
            }
        }
        if (__all(done)) break;
    }
    const int pix = py * IMG_W + px;
    img[pix]                   = cr + T * bg[0];
    img[IMG_H*IMG_W   + pix]   = cg + T * bg[1];
    img[2*IMG_H*IMG_W + pix]   = cb + T * bg[2];
}

extern "C" void kernel_launch(void* const* d_in, const int* in_sizes, int n_in,
                              void* d_out, int out_size, void* d_ws, size_t ws_size,
                              hipStream_t stream) {
    const float* means3D    = (const float*)d_in[0];
    // d_in[1] = means2D (unused by reference math)
    const float* opacities  = (const float*)d_in[2];
    const float* colors     = (const float*)d_in[3];
    const float* scales     = (const float*)d_in[4];
    const float* rotations  = (const float*)d_in[5];
    const float* viewmatrix = (const float*)d_in[6];
    const float* projmatrix = (const float*)d_in[7];
    const float* bg         = (const float*)d_in[8];

    float* img   = (float*)d_out;                   // 3*256*256
    float* radii = (float*)d_out + 3*IMG_H*IMG_W;   // 512 (as float values)
    float4* Gs   = (float4*)d_ws;                   // 512 float4
    float4* Ga   = Gs + N_G;                        // 512 float4
    float2* Gb   = (float2*)(Ga + N_G);             // 512 float2

    gs_prep<<<1, N_G, 0, stream>>>(means3D, opacities, colors, scales,
                                   rotations, viewmatrix, projmatrix,
                                   Gs, Ga, Gb, radii);
    gs_raster<<<(IMG_W/8)*(IMG_H/8), 64, 0, stream>>>(Gs, Ga, Gb, bg, img);
}

// Round 9
// 19.270 us; speedup vs baseline: 3.2503x; 1.5975x over previous
//
#include <hip/hip_runtime.h>
#include <hip/hip_fp16.h>
#include <math.h>

#define N_G    512
#define IMG_H  256
#define IMG_W  256

// Kernel A: 8 blocks x 64 threads, one gaussian per thread, registers only.
// ORIGINAL-ORDER packed planes (no global sort — depth ordering happens
// per-tile over the tiny covering subset in kernel B):
//   Gs[g] = {px, py, cull_rad, tz}        (scan plane; rad<0 = culled)
//   Ga[g] = {-0.5A, -B, -0.5C, ln(op)}    (blend quadratic plane)
//   Gb[g] = {half2(col_r,col_g), col_b}   (color plane)
__global__ __launch_bounds__(64) void gs_prep(
    const float* __restrict__ means3D,
    const float* __restrict__ opacities,
    const float* __restrict__ colors,
    const float* __restrict__ scales,
    const float* __restrict__ rotations,
    const float* __restrict__ viewmatrix,
    const float* __restrict__ projmatrix,
    float4* __restrict__ Gs,
    float4* __restrict__ Ga,
    float2* __restrict__ Gb,
    float* __restrict__ radii_out)
{
    const int g = blockIdx.x * 64 + threadIdx.x;

    float VM[16], PM[16];
    #pragma unroll
    for (int i = 0; i < 16; ++i) { VM[i] = viewmatrix[i]; PM[i] = projmatrix[i]; }

    const float mx = means3D[g*3+0], my = means3D[g*3+1], mz = means3D[g*3+2];
    float rq = rotations[g*4+0], xq = rotations[g*4+1], yq = rotations[g*4+2], zq = rotations[g*4+3];
    const float qn = sqrtf(rq*rq + xq*xq + yq*yq + zq*zq);
    rq /= qn; xq /= qn; yq /= qn; zq /= qn;
    const float R00 = 1.f - 2.f*(yq*yq + zq*zq);
    const float R01 = 2.f*(xq*yq - rq*zq);
    const float R02 = 2.f*(xq*zq + rq*yq);
    const float R10 = 2.f*(xq*yq + rq*zq);
    const float R11 = 1.f - 2.f*(xq*xq + zq*zq);
    const float R12 = 2.f*(yq*zq - rq*xq);
    const float R20 = 2.f*(xq*zq - rq*yq);
    const float R21 = 2.f*(yq*zq + rq*xq);
    const float R22 = 1.f - 2.f*(xq*xq + yq*yq);
    float s0 = scales[g*3+0], s1 = scales[g*3+1], s2 = scales[g*3+2];
    s0 *= s0; s1 *= s1; s2 *= s2;
    const float S00 = R00*R00*s0 + R01*R01*s1 + R02*R02*s2;
    const float S01 = R00*R10*s0 + R01*R11*s1 + R02*R12*s2;
    const float S02 = R00*R20*s0 + R01*R21*s1 + R02*R22*s2;
    const float S11 = R10*R10*s0 + R11*R11*s1 + R12*R12*s2;
    const float S12 = R10*R20*s0 + R11*R21*s1 + R12*R22*s2;
    const float S22 = R20*R20*s0 + R21*R21*s1 + R22*R22*s2;

    const float pv0 = VM[0]*mx + VM[1]*my + VM[2]*mz  + VM[3];
    const float pv1 = VM[4]*mx + VM[5]*my + VM[6]*mz  + VM[7];
    const float tz  = VM[8]*mx + VM[9]*my + VM[10]*mz + VM[11];
    const float FX = 256.f, FY = 256.f, limx = 0.65f, limy = 0.65f;
    const float tx = fminf(fmaxf(pv0/tz, -limx), limx) * tz;
    const float ty = fminf(fmaxf(pv1/tz, -limy), limy) * tz;
    const float itz = 1.f / tz, itz2 = itz*itz;
    const float J00 = FX*itz, J02 = -FX*tx*itz2;
    const float J11 = FY*itz, J12 = -FY*ty*itz2;
    const float T00 = J00*VM[0] + J02*VM[8];
    const float T01 = J00*VM[1] + J02*VM[9];
    const float T02 = J00*VM[2] + J02*VM[10];
    const float T10 = J11*VM[4] + J12*VM[8];
    const float T11 = J11*VM[5] + J12*VM[9];
    const float T12 = J11*VM[6] + J12*VM[10];
    const float u0 = T00*S00 + T01*S01 + T02*S02;
    const float u1 = T00*S01 + T01*S11 + T02*S12;
    const float u2 = T00*S02 + T01*S12 + T02*S22;
    const float v0 = T10*S00 + T11*S01 + T12*S02;
    const float v1 = T10*S01 + T11*S11 + T12*S12;
    const float v2 = T10*S02 + T11*S12 + T12*S22;
    const float c00 = u0*T00 + u1*T01 + u2*T02;
    const float c01 = u0*T10 + u1*T11 + u2*T12;
    const float c11 = v0*T10 + v1*T11 + v2*T12;
    const float a = c00 + 0.3f, b = c01, c = c11 + 0.3f;
    const float det = a*c - b*b;
    const float inv_det = 1.f/det;
    float conA = c*inv_det, conB = -b*inv_det, conC = a*inv_det;
    const float ph0 = PM[0]*mx  + PM[1]*my  + PM[2]*mz  + PM[3];
    const float ph1 = PM[4]*mx  + PM[5]*my  + PM[6]*mz  + PM[7];
    const float ph3 = PM[12]*mx + PM[13]*my + PM[14]*mz + PM[15];
    const float pw = 1.f/(ph3 + 1e-7f);
    const float pix_x = ((ph0*pw + 1.f)*(float)IMG_W - 1.f)*0.5f;
    const float pix_y = ((ph1*pw + 1.f)*(float)IMG_H - 1.f)*0.5f;
    const float mid = 0.5f*(a + c);
    const float lam = mid + sqrtf(fmaxf(0.1f, mid*mid - det));
    const bool valid = (tz > 0.2f) && (det > 0.f);
    float op = opacities[g];
    if (!valid) { conA = conB = conC = 0.f; op = 0.f; }

    radii_out[g] = valid ? ceilf(3.f*sqrtf(lam)) : 0.f;

    // Conservative cull radius: al >= 1/255 needs |d|^2 <= 2*lam*ln(255*op)
    // (lam >= lambda_max of regularized cov2d: sqrt arg is clamped upward).
    float rad = -1.f;
    if (valid && op * 255.f > 1.f) {
        const float r = sqrtf(2.f * lam * logf(255.f * op)) + 0.01f;
        if (pix_x + r >= 0.f && pix_x - r <= (float)(IMG_W-1) &&
            pix_y + r >= 0.f && pix_y - r <= (float)(IMG_H-1))
            rad = r;
    }

    const float lnop = logf(op);   // op==0 -> -inf -> alpha 0 (and rad<0 anyway)
    const float rg = __builtin_bit_cast(float, __floats2half2_rn(colors[g*3+0], colors[g*3+1]));
    Gs[g] = make_float4(pix_x, pix_y, rad, tz);
    Ga[g] = make_float4(-0.5f*conA, -conB, -0.5f*conC, lnop);
    Gb[g] = make_float2(rg, colors[g*3+2]);
}

// Kernel B: 512 blocks x 128 threads, one 16x8 tile per block.
// ONE global epoch: unconditionally stage 4 strided gaussians' planes into
// registers (12 independent loads, one drain). Hits are atomically appended
// to UNORDERED LDS arrays straight from registers. Then LDS-only: stable
// rank over the nc-entry subset by (tz, idx) -> ordered arrays -> blend.
__global__ __launch_bounds__(128) void gs_raster(
    const float4* __restrict__ Gs,
    const float4* __restrict__ Ga,
    const float2* __restrict__ Gb,
    const float* __restrict__ bg,
    float* __restrict__ img)
{
    __shared__ int    s_n;
    __shared__ float  s_tz[N_G];
    __shared__ int    s_id[N_G];
    __shared__ float2 uP[N_G];   // unordered append
    __shared__ float4 uA[N_G];
    __shared__ float2 uC[N_G];
    __shared__ float2 oP[N_G];   // depth-ordered
    __shared__ float4 oA[N_G];
    __shared__ float2 oC[N_G];

    const int tid = threadIdx.x;
    const int bx = blockIdx.x & 15, by = blockIdx.x >> 4;   // 16x32 grid of 16x8 tiles
    const float x0 = (float)(bx * 16), x1 = x0 + 15.f;
    const float y0 = (float)(by * 8),  y1 = y0 + 7.f;

    if (tid == 0) s_n = 0;

    // single load burst: all 12 loads issue before any use
    float4 s[4], a[4];
    float2 c[4];
    #pragma unroll
    for (int k = 0; k < 4; ++k) {
        const int g = k * 128 + tid;
        s[k] = Gs[g];
        a[k] = Ga[g];
        c[k] = Gb[g];
    }
    __syncthreads();   // covers s_n init

    // append hits (register -> LDS, no second global epoch)
    #pragma unroll
    for (int k = 0; k < 4; ++k) {
        const bool hit = (s[k].z > 0.f &&
                          s[k].x + s[k].z >= x0 && s[k].x - s[k].z <= x1 &&
                          s[k].y + s[k].z >= y0 && s[k].y - s[k].z <= y1);
        if (hit) {
            const int p = atomicAdd(&s_n, 1);
            s_tz[p] = s[k].w;
            s_id[p] = k * 128 + tid;
            uP[p] = make_float2(s[k].x, s[k].y);
            uA[p] = a[k];
            uC[p] = c[k];
        }
    }
    __syncthreads();

    const int nc  = s_n;
    const int ncp = (nc + 7) & ~7;

    // LDS-only stable rank by (tz, original idx) == stable global argsort
    // restricted to the covering subset; reorder into oP/oA/oC.
    for (int i = tid; i < nc; i += 128) {
        const float tz = s_tz[i];
        const int   id = s_id[i];
        int r = 0;
        for (int j = 0; j < nc; ++j) {
            const float tj = s_tz[j];
            r += (tj < tz) || (tj == tz && s_id[j] < id);
        }
        oP[r] = uP[i];
        oA[r] = uA[i];
        oC[r] = uC[i];
    }
    for (int i = nc + tid; i < ncp; i += 128) {   // pad: lnop=-1e30 -> skipped
        oP[i] = make_float2(0.f, 0.f);
        oA[i] = make_float4(0.f, 0.f, 0.f, -1e30f);
        oC[i] = make_float2(0.f, 0.f);
    }
    __syncthreads();

    // front-to-back blend, one pixel per thread
    const int px = bx * 16 + (tid & 15), py = by * 8 + (tid >> 4);
    const float fx = (float)px, fy = (float)py;

    float T = 1.f, cr = 0.f, cg = 0.f, cb = 0.f;
    bool done = false;
    for (int base = 0; base < ncp; base += 8) {
        #pragma unroll
        for (int u = 0; u < 8; ++u) {
            const int i = base + u;
            const float2 pP = oP[i];
            const float4 pA = oA[i];
            const float2 pC = oC[i];
            const float dx = pP.x - fx;
            const float dy = pP.y - fy;
            const float power = pA.x*dx*dx + pA.y*dx*dy + pA.z*dy*dy;
            const float al = fminf(0.99f, __expf(power + pA.w));
            if (!done && !(power > 0.f || al < (1.0f/255.0f))) {
                const float Tnew = T * (1.f - al);
                if (Tnew < 1e-4f) { T = Tnew; done = true; }
                else {
                    const float wgt = al * T;
                    const float2 rg = __half22float2(__builtin_bit_cast(__half2, pC.x));
                    cr += wgt * rg.x;
                    cg += wgt * rg.y;
                    cb += wgt * pC.y;
                    T = Tnew;
                }
            }
        }
        if (__all(done)) break;
    }
    const int pix = py * IMG_W + px;
    img[pix]                   = cr + T * bg[0];
    img[IMG_H*IMG_W   + pix]   = cg + T * bg[1];
    img[2*IMG_H*IMG_W + pix]   = cb + T * bg[2];
}

extern "C" void kernel_launch(void* const* d_in, const int* in_sizes, int n_in,
                              void* d_out, int out_size, void* d_ws, size_t ws_size,
                              hipStream_t stream) {
    const float* means3D    = (const float*)d_in[0];
    // d_in[1] = means2D (unused by reference math)
    const float* opacities  = (const float*)d_in[2];
    const float* colors     = (const float*)d_in[3];
    const float* scales     = (const float*)d_in[4];
    const float* rotations  = (const float*)d_in[5];
    const float* viewmatrix = (const float*)d_in[6];
    const float* projmatrix = (const float*)d_in[7];
    const float* bg         = (const float*)d_in[8];

    float* img   = (float*)d_out;                   // 3*256*256
    float* radii = (float*)d_out + 3*IMG_H*IMG_W;   // 512 (as float values)
    float4* Gs   = (float4*)d_ws;                   // 512 float4
    float4* Ga   = Gs + N_G;                        // 512 float4
    float2* Gb   = (float2*)(Ga + N_G);             // 512 float2

    gs_prep<<<8, 64, 0, stream>>>(means3D, opacities, colors, scales,
                                  rotations, viewmatrix, projmatrix,
                                  Gs, Ga, Gb, radii);
    gs_raster<<<(IMG_W/16)*(IMG_H/8), 128, 0, stream>>>(Gs, Ga, Gb, bg, img);
}